// Round 12
// baseline (506.076 us; speedup 1.0000x reference)
//
#include <hip/hip_runtime.h>

#define T_LEN 1024
#define M_DIM 128
#define B_NUM 64

typedef _Float16 h2 __attribute__((ext_vector_type(2)));

#if __has_builtin(__builtin_amdgcn_fdot2)
#define DOT2(a, b, c) __builtin_amdgcn_fdot2((a), (b), (c), false)
#else
__device__ __forceinline__ float DOT2(h2 a, h2 b, float c) {
  return fmaf((float)a.x, (float)b.x, fmaf((float)a.y, (float)b.y, c));
}
#endif

// DPP lane-move (VALU pipe). bound_ctrl=true. Ctrls: 0xB1 (quad xor1),
// 0x4E (quad xor2), 0x141 (row_half_mirror: lane i in each 8-half gets lane
// 7-i), 0x140 (row_mirror), 0x142 (row_bcast15).
// NOTE (r11 bug): row_shr:N moves data toward HIGHER lanes (lane i receives
// lane i-N) — it is NOT a partner-fetch toward i+N. Partner fetch here uses
// 0x141: lane 0 <- lane 7 (j+1), lane 8 <- lane 15 (j+3). Field-proven.
template<int CTRL>
__device__ __forceinline__ float dpp_mov(float x) {
  int y = __builtin_amdgcn_update_dpp(0, __float_as_int(x), CTRL, 0xf, 0xf, true);
  return __int_as_float(y);
}

__device__ __forceinline__ unsigned pack_f16(float a, float bq) {
  h2 hv; hv.x = (_Float16)a; hv.y = (_Float16)bq;   // RTE, matches r8 (absmax 0)
  return __builtin_bit_cast(unsigned, hv);
}

// One block (512 thr, 8 waves) per batch — r6/r8-proven skeleton (relaxed
// barrier, parity red, lag-1 Z, 2^-8 headroom, hoisted sY) with the lean
// datapath: lane = (j = tid>>2, igrp = tid&3). Lane owns ONE output j and
// i-quarter igrp as 16 f16 dot2 pairs (16 VGPRs). Per step: 4 broadcast
// ds_read_b128, 16 v_dot2_f32_f16, 2 quad-DPP reduce stages, 1 exp; partner
// fetch via 0x141 half-mirror + RTE pack, single-lane b32 write. Z: 3-DPP
// tree, lanes 16/48 write half-wave maxes to redf[2][16] (parity).
__global__ __launch_bounds__(512, 1) void crf_fwd(
    const float* __restrict__ P, const float* __restrict__ A,
    const int* __restrict__ Y, const int* __restrict__ L,
    float* __restrict__ out)
{
  const int b    = blockIdx.x;
  const int tid  = threadIdx.x;
  const int lane = tid & 63;
  const int wid  = tid >> 6;      // 0..7
  const int j    = tid >> 2;      // 0..127 (4 lanes per j)
  const int igrp = tid & 3;       // i-quarter: pairs igrp*16 .. igrp*16+15

  __shared__ __align__(16) unsigned u_pk[2][64];   // h2 pair m = states {2m,2m+1}
  __shared__ __align__(16) float redf[2][16];      // parity-buffered half-wave maxes
  __shared__ float red_sum[8];
  __shared__ float sY_sh[8];
  __shared__ float boot[8];

  const int Lb = L[b];
  const float* Pb = P + (size_t)b * T_LEN * M_DIM;
  const int*   Yb = Y + b * T_LEN;

#define BARRIER_RELAXED() do { \
    asm volatile("s_waitcnt lgkmcnt(0)" ::: "memory"); \
    __builtin_amdgcn_s_barrier(); } while (0)

  // W: w[m] = f16{exp(A[2*(igrp*16+m)][j]), exp(A[2*(igrp*16+m)+1][j])}
  h2 w[16];
  #pragma unroll
  for (int m = 0; m < 16; ++m) {
    const int pr = igrp * 16 + m;
    h2 hv;
    hv.x = (_Float16)__expf(A[(2 * pr) * M_DIM + j]);
    hv.y = (_Float16)__expf(A[(2 * pr + 1) * M_DIM + j]);
    w[m] = hv;
  }

  // ---- path score sY: no sequential dependency, gather in parallel ----
  float mySY = 0.f;
  for (int tt = tid; tt < Lb; tt += 512) {
    int yt = Yb[tt];
    float term = Pb[tt * M_DIM + yt];
    term += (tt == 0) ? A[M_DIM * M_DIM + yt] : A[Yb[tt - 1] * M_DIM + yt];
    mySY += term;
  }
  #pragma unroll
  for (int d = 1; d < 64; d <<= 1) mySY += __shfl_xor(mySY, d);
  if (lane == 0) sY_sh[wid] = mySY;

  // ---- t = 0: m0-normalize (stored max = 1.0 exactly) ----
  float s0 = Pb[j] + A[M_DIM * M_DIM + j];
  {
    float mm = s0;
    #pragma unroll
    for (int d = 1; d < 64; d <<= 1) mm = fmaxf(mm, __shfl_xor(mm, d));
    if (lane == 0) boot[wid] = mm;
  }
  if (tid < 16) redf[1][tid] = 1.0f;   // Z for step 1: true max of u0 is 1
  __syncthreads();
  float C = boot[0];
  #pragma unroll
  for (int q = 1; q < 8; ++q) C = fmaxf(C, boot[q]);
  float un = __expf(s0 - C);
  {
    float nb = dpp_mov<0x141>(un);     // half-mirror: lane0<-7 (j+1), lane8<-15 (j+3)
    if ((tid & 7) == 0) u_pk[0][tid >> 3] = pack_f16(un, nb);
  }
  float p_cur = Pb[M_DIM + j];         // row t=1 (always a valid row)
  if (Lb == 1) {
    float s = (igrp == 0) ? un : 0.f;
    #pragma unroll
    for (int d = 1; d < 64; d <<= 1) s += __shfl_xor(s, d);
    if (lane == 0) red_sum[wid] = s;
  }
  __syncthreads();
  if (Lb == 1) goto finish;

// Sub-step. PAR = t&1 (compile-time): read redf[PAR], write redf[PAR^1].
#define CRF_STEP(S, PAR, PN)                                               \
  {                                                                        \
    const float4* rf = (const float4*)&redf[PAR][0];                       \
    float4 ra = rf[0], rb = rf[1], rc = rf[2], rd = rf[3];                 \
    float Z = fmaxf(fmaxf(fmaxf(ra.x, ra.y), fmaxf(ra.z, ra.w)),           \
                    fmaxf(fmaxf(rb.x, rb.y), fmaxf(rb.z, rb.w)));          \
    Z = fmaxf(Z, fmaxf(fmaxf(fmaxf(rc.x, rc.y), fmaxf(rc.z, rc.w)),        \
                       fmaxf(fmaxf(rd.x, rd.y), fmaxf(rd.z, rd.w))));      \
    Z = fmaxf(Z, 1e-30f);                                                  \
    float iZ = __builtin_amdgcn_rcpf(Z) * 0.00390625f;                     \
    C += __logf(Z) + 5.54517744f;   /* log Z + 8 ln 2 */                   \
    float ep = __expf(p_cur) * iZ;                                         \
    const uint4* u4 = (const uint4*)&u_pk[cur][igrp * 16];                 \
    uint4 uu0 = u4[0], uu1 = u4[1], uu2 = u4[2], uu3 = u4[3];              \
    float a0 = 0.f, a1 = 0.f, a2 = 0.f, a3 = 0.f;                          \
    a0 = DOT2(__builtin_bit_cast(h2, uu0.x), w[0],  a0);                   \
    a1 = DOT2(__builtin_bit_cast(h2, uu0.y), w[1],  a1);                   \
    a2 = DOT2(__builtin_bit_cast(h2, uu0.z), w[2],  a2);                   \
    a3 = DOT2(__builtin_bit_cast(h2, uu0.w), w[3],  a3);                   \
    a0 = DOT2(__builtin_bit_cast(h2, uu1.x), w[4],  a0);                   \
    a1 = DOT2(__builtin_bit_cast(h2, uu1.y), w[5],  a1);                   \
    a2 = DOT2(__builtin_bit_cast(h2, uu1.z), w[6],  a2);                   \
    a3 = DOT2(__builtin_bit_cast(h2, uu1.w), w[7],  a3);                   \
    a0 = DOT2(__builtin_bit_cast(h2, uu2.x), w[8],  a0);                   \
    a1 = DOT2(__builtin_bit_cast(h2, uu2.y), w[9],  a1);                   \
    a2 = DOT2(__builtin_bit_cast(h2, uu2.z), w[10], a2);                   \
    a3 = DOT2(__builtin_bit_cast(h2, uu2.w), w[11], a3);                   \
    a0 = DOT2(__builtin_bit_cast(h2, uu3.x), w[12], a0);                   \
    a1 = DOT2(__builtin_bit_cast(h2, uu3.y), w[13], a1);                   \
    a2 = DOT2(__builtin_bit_cast(h2, uu3.z), w[14], a2);                   \
    a3 = DOT2(__builtin_bit_cast(h2, uu3.w), w[15], a3);                   \
    float v = (a0 + a1) + (a2 + a3);                                       \
    v += dpp_mov<0xB1>(v);   /* quad xor1 */                               \
    v += dpp_mov<0x4E>(v);   /* quad xor2 -> full 128-dot for j */         \
    un = v * ep;                                                           \
    {                                                                      \
      float nb = dpp_mov<0x141>(un);   /* partner j+1 / j+3 (see note) */  \
      if ((tid & 7) == 0) u_pk[cur ^ 1][tid >> 3] = pack_f16(un, nb);      \
    }                                                                      \
    { /* lag-1 Z tree (un uniform per quad) */                             \
      float zm = un;                                                       \
      zm = fmaxf(zm, dpp_mov<0x141>(zm));   /* 8-uniform */                \
      zm = fmaxf(zm, dpp_mov<0x140>(zm));   /* 16-uniform */               \
      zm = fmaxf(zm, dpp_mov<0x142>(zm));   /* lane16=max(r0,r1),          \
                                               lane48=max(r2,r3) */       \
      if (lane == 16) redf[(PAR) ^ 1][2 * wid] = zm;                       \
      if (lane == 48) redf[(PAR) ^ 1][2 * wid + 1] = zm;                   \
    }                                                                      \
    const bool last_ = (tb + (S) == Lb - 1);                               \
    if (last_) {                                                           \
      float s = (igrp == 0) ? un : 0.f;                                    \
      _Pragma("unroll")                                                    \
      for (int d = 1; d < 64; d <<= 1) s += __shfl_xor(s, d);              \
      if (lane == 0) red_sum[wid] = s;                                     \
    }                                                                      \
    BARRIER_RELAXED();                                                     \
    if (last_) goto finish;                                                \
    p_cur = (PN);                                                          \
    cur ^= 1;                                                              \
  }

  {
    int cur = 0;
    int tb  = 1;   // iteration handles steps tb..tb+7; tb stays odd
    const float* Pq = Pb + j;
    for (;;) {
      // Burst-prefetch P rows tb+1..tb+8 (clamped) into static regs;
      // raw s_barrier never drains vmcnt -> loads stay in flight.
      float q0, q1, q2, q3, q4, q5, q6, q7;
      {
        int r;
        r = tb + 1; r = r < T_LEN ? r : T_LEN - 1; q0 = Pq[r * M_DIM];
        r = tb + 2; r = r < T_LEN ? r : T_LEN - 1; q1 = Pq[r * M_DIM];
        r = tb + 3; r = r < T_LEN ? r : T_LEN - 1; q2 = Pq[r * M_DIM];
        r = tb + 4; r = r < T_LEN ? r : T_LEN - 1; q3 = Pq[r * M_DIM];
        r = tb + 5; r = r < T_LEN ? r : T_LEN - 1; q4 = Pq[r * M_DIM];
        r = tb + 6; r = r < T_LEN ? r : T_LEN - 1; q5 = Pq[r * M_DIM];
        r = tb + 7; r = r < T_LEN ? r : T_LEN - 1; q6 = Pq[r * M_DIM];
        r = tb + 8; r = r < T_LEN ? r : T_LEN - 1; q7 = Pq[r * M_DIM];
      }
      // t = tb+S: odd for even S (tb odd) -> PAR = 1,0,1,0,...
      CRF_STEP(0, 1, q0)
      CRF_STEP(1, 0, q1)
      CRF_STEP(2, 1, q2)
      CRF_STEP(3, 0, q3)
      CRF_STEP(4, 1, q4)
      CRF_STEP(5, 0, q5)
      CRF_STEP(6, 1, q6)
      CRF_STEP(7, 0, q7)
      tb += 8;
    }
  }

finish:
  if (tid == 0) {
    float s = 0.f, sy = 0.f;
    #pragma unroll
    for (int q2 = 0; q2 < 8; ++q2) { s += red_sum[q2]; sy += sY_sh[q2]; }
    out[b] = __logf(s) + C - sy;
  }
}

extern "C" void kernel_launch(void* const* d_in, const int* in_sizes, int n_in,
                              void* d_out, int out_size, void* d_ws, size_t ws_size,
                              hipStream_t stream) {
  const float* P = (const float*)d_in[0];
  const float* A = (const float*)d_in[1];
  const int*   Y = (const int*)d_in[2];
  const int*   L = (const int*)d_in[3];
  float* o = (float*)d_out;
  hipLaunchKernelGGL(crf_fwd, dim3(B_NUM), dim3(512), 0, stream, P, A, Y, L, o);
}